// Round 2
// baseline (155.554 us; speedup 1.0000x reference)
//
#include <hip/hip_runtime.h>
#include <hip/hip_bf16.h>
#include <stdint.h>

#define NS 8192
#define NHALF 4096
#define DIM 256
#define BLK 128
#define BK 64
#define NTILES (NS / BLK)        // 64
#define HALF_TILES (NHALF / BLK) // 32
#define NTRI (NTILES * (NTILES + 1) / 2)  // 2080 upper-tri tiles
#define PREP_BLOCKS 256

typedef __attribute__((ext_vector_type(8))) short bf16x8;
typedef __attribute__((ext_vector_type(4))) float f32x4;
typedef __attribute__((ext_vector_type(2))) float f32x2;
typedef __attribute__((ext_vector_type(8))) unsigned short u16x8;

// workspace layout (bytes)
#define XB_OFF   0                         // bf16 X: 8192*256*2 = 4 MiB
#define SQ_OFF   (NS * DIM * 2)            // f32 sq[8192] = 32 KiB
#define ACC_OFF  (SQ_OFF + NS * 4)         // f64 signed kernel sum (8)
#define CNT_OFF  (ACC_OFF + 8)             // u32 done-counter (4)
#define S1_OFF   (ACC_OFF + 12)            // f32 sum ||x||^2 (4)
#define CS_OFF   (ACC_OFF + 16)            // f32 colsum[256] (1 KiB)
#define ZERO_BYTES (16 + DIM * 4)
#define WS_NEED  (CS_OFF + DIM * 4)

__device__ __forceinline__ unsigned short f2bf(float f) {
  unsigned int u = __float_as_uint(f);
  u += 0x7fffu + ((u >> 16) & 1u);   // round-to-nearest-even
  return (unsigned short)(u >> 16);
}
__device__ __forceinline__ float bf2f(unsigned short h) {
  return __uint_as_float(((unsigned int)h) << 16);
}

// ---- Kernel 1: convert to bf16, row ||x||^2, atomic column sums + S1 ----
// 256 blocks x 256 threads, 32 rows/block.
__global__ __launch_bounds__(256) void mmd_prep(
    const float* __restrict__ src, const float* __restrict__ tgt,
    unsigned short* __restrict__ Xb, float* __restrict__ sq,
    float* __restrict__ colsum, float* __restrict__ S1p) {
  int tid = threadIdx.x;
  int lane32 = tid & 31;               // 32 threads per row
  int rgrp = tid >> 5;                 // 8 rows in flight
  int c = lane32 * 8;                  // 8 cols per thread
  int rowBase = blockIdx.x * 32;

  float colpart[8];
#pragma unroll
  for (int j = 0; j < 8; ++j) colpart[j] = 0.f;
  float ssum = 0.f;                    // row-sq partial (valid at lane32==0)

#pragma unroll
  for (int p = 0; p < 4; ++p) {
    int row = rowBase + p * 8 + rgrp;
    const float* X = (row < NHALF) ? (src + (size_t)row * DIM)
                                   : (tgt + (size_t)(row - NHALF) * DIM);
    float4 v0 = *(const float4*)(X + c);
    float4 v1 = *(const float4*)(X + c + 4);
    float vals[8] = {v0.x, v0.y, v0.z, v0.w, v1.x, v1.y, v1.z, v1.w};
    u16x8 h;
    float s = 0.f;
#pragma unroll
    for (int j = 0; j < 8; ++j) {
      unsigned short b = f2bf(vals[j]);
      h[j] = b;
      float rb = bf2f(b);
      s += rb * rb;
      colpart[j] += rb;
    }
    *(u16x8*)(Xb + (size_t)row * DIM + c) = h;   // 16B store
    // row-sq reduce over the 32 lanes of this row (no atomics)
    for (int o = 16; o > 0; o >>= 1) s += __shfl_down(s, o, 32);
    if (lane32 == 0) { sq[row] = s; ssum += s; }
  }

  // block-level column reduce (8-way, via LDS), then one atomic per column
  __shared__ float cp[8][DIM];
  __shared__ float rowsum[8];
  *(float4*)&cp[rgrp][c]     = make_float4(colpart[0], colpart[1], colpart[2], colpart[3]);
  *(float4*)&cp[rgrp][c + 4] = make_float4(colpart[4], colpart[5], colpart[6], colpart[7]);
  if (lane32 == 0) rowsum[rgrp] = ssum;
  __syncthreads();
  float s8 = 0.f;
#pragma unroll
  for (int r = 0; r < 8; ++r) s8 += cp[r][tid];
  atomicAdd(&colsum[tid], s8);
  if (tid == 0) {
    float t = 0.f;
#pragma unroll
    for (int r = 0; r < 8; ++r) t += rowsum[r];
    atomicAdd(S1p, t);
  }
}

// ---- Kernel 2: Gram tile + fused multi-bandwidth exp epilogue ----
// Triangular 1-D grid: only bi <= bj tiles are launched.
// Bandwidth is recomputed per-wave from colsum/S1 (prep finished: stream order).
// Last block to finish writes the final scalar (threadfence + counter).
// launch_bounds(256,3): VGPR cap ~170 >= ~144 needed (80 arch + 64 acc) -> no
// spill (round-1's (256,4) cap=128 spilled acc: WRITE_SIZE 2.2 MB, 3x slower),
// and 3 blocks/CU instead of 2.
__global__ __launch_bounds__(256, 3) void mmd_gram(
    const unsigned short* __restrict__ Xb, const float* __restrict__ sq,
    const float* __restrict__ colsum, const float* __restrict__ S1p,
    double* __restrict__ accK, unsigned int* __restrict__ cnt,
    float* __restrict__ out) {
  int l = blockIdx.x;
  int bj = (int)((sqrtf(8.f * (float)l + 1.f) - 1.f) * 0.5f);
  while ((bj + 1) * (bj + 2) / 2 <= l) bj++;
  while (bj * (bj + 1) / 2 > l) bj--;
  int bi = l - bj * (bj + 1) / 2;

  __shared__ __align__(16) unsigned short As[BLK * BK];
  __shared__ __align__(16) unsigned short Bs[BLK * BK];
  __shared__ float red4[4];
  int tid = threadIdx.x;
  int wave = tid >> 6;
  int lane = tid & 63;
  int rowBase = bi * BLK, colBase = bj * BLK;
  int wr = (wave >> 1) * 64;   // wave's 64x64 quadrant
  int wc = (wave & 1) * 64;

  // per-wave bandwidth: S2 = sum_d colsum_d^2 via butterfly reduce (no barrier)
  float s2p = 0.f;
#pragma unroll
  for (int i = 0; i < 4; ++i) {
    float cv = colsum[i * 64 + lane];
    s2p += cv * cv;
  }
#pragma unroll
  for (int o = 32; o > 0; o >>= 1) s2p += __shfl_xor(s2p, o);
  float S1 = *S1p;
  double sum_l2 = 2.0 * (double)NS * (double)S1 - 2.0 * (double)s2p;
  double bw = sum_l2 / ((double)NS * (double)NS - (double)NS) * 0.25;
  // arg for widest kernel: -0.0625*log2(e)*l2/bw ; l2 = sqr + sqc - 2*acc
  float cE = (float)(-1.4426950408889634 * 0.0625 / bw);
  float t2 = -2.f * cE;

  f32x4 acc[4][4];
#pragma unroll
  for (int m = 0; m < 4; ++m)
#pragma unroll
    for (int n = 0; n < 4; ++n) acc[m][n] = (f32x4){0.f, 0.f, 0.f, 0.f};

  for (int kt = 0; kt < DIM; kt += BK) {
    __syncthreads();  // previous compute done before overwrite
#pragma unroll
    for (int it = 0; it < 4; ++it) {
      int idx = it * 256 + tid;        // 0..1023, 16B each
      int r = idx >> 3;                // tile row 0..127
      int g = idx & 7;                 // 16B group within row
      int gs = g ^ (r & 7);            // pre-swizzled SOURCE (rule #21)
      const unsigned short* ga = Xb + (size_t)(rowBase + r) * DIM + kt + gs * 8;
      __builtin_amdgcn_global_load_lds(
          (const __attribute__((address_space(1))) void*)ga,
          (__attribute__((address_space(3))) void*)(As + idx * 8), 16, 0, 0);
      const unsigned short* gb = Xb + (size_t)(colBase + r) * DIM + kt + gs * 8;
      __builtin_amdgcn_global_load_lds(
          (const __attribute__((address_space(1))) void*)gb,
          (__attribute__((address_space(3))) void*)(Bs + idx * 8), 16, 0, 0);
    }
    __syncthreads();  // drains vmcnt(0): staged data ready

#pragma unroll
    for (int ks = 0; ks < 2; ++ks) {
      bf16x8 af[4], bfr[4];
      int kg = ks * 4 + (lane >> 4);   // 16B group index of this lane's k-slice
#pragma unroll
      for (int m = 0; m < 4; ++m) {
        int r = wr + m * 16 + (lane & 15);
        af[m] = *(const bf16x8*)(As + r * BK + (kg ^ (r & 7)) * 8);
      }
#pragma unroll
      for (int n = 0; n < 4; ++n) {
        int r = wc + n * 16 + (lane & 15);
        bfr[n] = *(const bf16x8*)(Bs + r * BK + (kg ^ (r & 7)) * 8);
      }
#pragma unroll
      for (int m = 0; m < 4; ++m)
#pragma unroll
        for (int n = 0; n < 4; ++n)
          acc[m][n] = __builtin_amdgcn_mfma_f32_16x16x32_bf16(
              af[m], bfr[n], acc[m][n], 0, 0, 0);
    }
  }

  // ---- epilogue: l2 -> sum of 5 Gaussians (1 exp2 + 4 squarings) ----
  // Processed in f32x2 pairs so the squaring/sum chain can lower to
  // v_pk_{fma,mul,add}_f32 (VOP3P) — worst case identical scalar ops.
  float b_[4];
  f32x2 aP[4][2];                      // cE*sq row terms, paired over r
  int r4 = (lane >> 4) * 4;
#pragma unroll
  for (int m = 0; m < 4; ++m)
#pragma unroll
    for (int p = 0; p < 2; ++p) {
      int rr = rowBase + wr + m * 16 + r4 + p * 2;
      aP[m][p] = (f32x2){cE * sq[rr], cE * sq[rr + 1]};
    }
#pragma unroll
  for (int n = 0; n < 4; ++n)
    b_[n] = cE * sq[colBase + wc + n * 16 + (lane & 15)];

  f32x2 ts = (f32x2){0.f, 0.f};
  f32x2 t2v = (f32x2){t2, t2};
#pragma unroll
  for (int m = 0; m < 4; ++m)
#pragma unroll
    for (int n = 0; n < 4; ++n) {
      f32x2 bv = (f32x2){b_[n], b_[n]};
#pragma unroll
      for (int p = 0; p < 2; ++p) {
        // C/D layout (m89): col = lane&15, row = (lane>>4)*4 + reg
        f32x2 a2 = (f32x2){acc[m][n][p * 2], acc[m][n][p * 2 + 1]};
        f32x2 arg = a2 * t2v + (aP[m][p] + bv);
        f32x2 e4;
        e4.x = exp2f(arg.x);
        e4.y = exp2f(arg.y);
        f32x2 e3 = e4 * e4;
        f32x2 e2 = e3 * e3;
        f32x2 e1 = e2 * e2;
        f32x2 e0 = e1 * e1;
        ts += ((e4 + e3) + (e2 + e1)) + e0;
      }
    }
  float tsum = ts.x + ts.y;

  // wave-level shuffle reduce, then tiny cross-wave combine
#pragma unroll
  for (int o = 32; o > 0; o >>= 1) tsum += __shfl_down(tsum, o);
  if (lane == 0) red4[wave] = tsum;
  __syncthreads();
  if (tid == 0) {
    float t = (red4[0] + red4[1]) + (red4[2] + red4[3]);
    float sign = ((bi < HALF_TILES) == (bj < HALF_TILES)) ? 1.f : -1.f;
    float factor = (bi == bj) ? sign : 2.f * sign;  // off-diag tiles doubled
    atomicAdd(accK, (double)(factor * t));
    __threadfence();
    unsigned int prev = atomicAdd(cnt, 1u);
    if (prev == NTRI - 1) {
      double tot = atomicAdd(accK, 0.0);  // coherent read at L2 point
      out[0] = (float)(tot / ((double)NHALF * (double)NHALF));
    }
  }
}

extern "C" void kernel_launch(void* const* d_in, const int* in_sizes, int n_in,
                              void* d_out, int out_size, void* d_ws, size_t ws_size,
                              hipStream_t stream) {
  if (ws_size < (size_t)WS_NEED) return;  // need ~4.2 MiB scratch
  const float* src = (const float*)d_in[0];
  const float* tgt = (const float*)d_in[1];
  char* ws = (char*)d_ws;
  unsigned short* Xb = (unsigned short*)(ws + XB_OFF);
  float* sq          = (float*)(ws + SQ_OFF);
  double* accK       = (double*)(ws + ACC_OFF);
  unsigned int* cnt  = (unsigned int*)(ws + CNT_OFF);
  float* S1p         = (float*)(ws + S1_OFF);
  float* colsum      = (float*)(ws + CS_OFF);

  hipMemsetAsync(ws + ACC_OFF, 0, ZERO_BYTES, stream);  // accK+cnt+S1+colsum
  mmd_prep<<<PREP_BLOCKS, 256, 0, stream>>>(src, tgt, Xb, sq, colsum, S1p);
  mmd_gram<<<NTRI, 256, 0, stream>>>(Xb, sq, colsum, S1p, accK, cnt,
                                     (float*)d_out);
}

// Round 3
// 87.446 us; speedup vs baseline: 1.7789x; 1.7789x over previous
//
#include <hip/hip_runtime.h>
#include <hip/hip_bf16.h>
#include <stdint.h>

#define NS 8192
#define NHALF 4096
#define DIM 256
#define BM 128
#define BN 64
#define BK 64
#define NMT (NS / BM)            // 64 M-tiles
#define NNT (NS / BN)            // 128 N-tiles
#define HALF_MT (NHALF / BM)     // 32
#define HALF_NT (NHALF / BN)     // 64
// per bi: bj in [2bi, 128) -> 128-2bi tiles; total sum = 4160
#define NTILES_TRI 4160
#define PREP_BLOCKS 256

typedef __attribute__((ext_vector_type(8))) short bf16x8;
typedef __attribute__((ext_vector_type(4))) float f32x4;
typedef __attribute__((ext_vector_type(8))) unsigned short u16x8;

// workspace layout (bytes) — round-0 proven layout
#define XB_OFF   0                         // bf16 X: 8192*256*2 = 4 MiB
#define SQ_OFF   (NS * DIM * 2)            // f32 sq[8192] = 32 KiB
#define PART_OFF (SQ_OFF + NS * 4)         // f32 partials[256][256] = 256 KiB
#define ACC_OFF  (PART_OFF + PREP_BLOCKS * DIM * 4)  // f64 signed kernel sum
#define C0_OFF   (ACC_OFF + 8)             // f32 log2e / bandwidth
#define WS_NEED  (C0_OFF + 16)

__device__ __forceinline__ unsigned short f2bf(float f) {
  unsigned int u = __float_as_uint(f);
  u += 0x7fffu + ((u >> 16) & 1u);   // round-to-nearest-even
  return (unsigned short)(u >> 16);
}
__device__ __forceinline__ float bf2f(unsigned short h) {
  return __uint_as_float(((unsigned int)h) << 16);
}

// ---- Kernel 1: convert to bf16, row ||x||^2, per-block column partials ----
// (round-0 exact)
__global__ __launch_bounds__(256) void mmd_prep(
    const float* __restrict__ src, const float* __restrict__ tgt,
    unsigned short* __restrict__ Xb, float* __restrict__ sq,
    float* __restrict__ partials) {
  int tid = threadIdx.x;
  int lane32 = tid & 31;
  int rgrp = tid >> 5;
  int c = lane32 * 8;
  int rowBase = blockIdx.x * 32;

  float colpart[8];
#pragma unroll
  for (int j = 0; j < 8; ++j) colpart[j] = 0.f;

#pragma unroll
  for (int p = 0; p < 4; ++p) {
    int row = rowBase + p * 8 + rgrp;
    const float* X = (row < NHALF) ? (src + (size_t)row * DIM)
                                   : (tgt + (size_t)(row - NHALF) * DIM);
    float4 v0 = *(const float4*)(X + c);
    float4 v1 = *(const float4*)(X + c + 4);
    float vals[8] = {v0.x, v0.y, v0.z, v0.w, v1.x, v1.y, v1.z, v1.w};
    u16x8 h;
    float s = 0.f;
#pragma unroll
    for (int j = 0; j < 8; ++j) {
      unsigned short b = f2bf(vals[j]);
      h[j] = b;
      float rb = bf2f(b);
      s += rb * rb;
      colpart[j] += rb;
    }
    *(u16x8*)(Xb + (size_t)row * DIM + c) = h;
    for (int o = 16; o > 0; o >>= 1) s += __shfl_down(s, o, 32);
    if (lane32 == 0) sq[row] = s;
  }

  __shared__ float cp[8][DIM];
  *(float4*)&cp[rgrp][c]     = make_float4(colpart[0], colpart[1], colpart[2], colpart[3]);
  *(float4*)&cp[rgrp][c + 4] = make_float4(colpart[4], colpart[5], colpart[6], colpart[7]);
  __syncthreads();
  float s8 = 0.f;
#pragma unroll
  for (int r = 0; r < 8; ++r) s8 += cp[r][tid];
  partials[blockIdx.x * DIM + tid] = s8;
}

// ---- Kernel 2: reduce partials + sq -> bandwidth -> c0 (round-0 exact) ----
__global__ __launch_bounds__(256) void mmd_band(
    const float* __restrict__ partials, const float* __restrict__ sq,
    float* __restrict__ c0out) {
  __shared__ double buf2[DIM];
  __shared__ float buf1[DIM];
  int tid = threadIdx.x;
  float cs = 0.f;
  for (int b = 0; b < PREP_BLOCKS; ++b) cs += partials[b * DIM + tid];
  float s1 = 0.f;
  for (int k = 0; k < NS / DIM; ++k) s1 += sq[k * DIM + tid];
  buf2[tid] = (double)cs * (double)cs;
  buf1[tid] = s1;
  __syncthreads();
  for (int o = 128; o > 0; o >>= 1) {
    if (tid < o) { buf2[tid] += buf2[tid + o]; buf1[tid] += buf1[tid + o]; }
    __syncthreads();
  }
  if (tid == 0) {
    double S1 = (double)buf1[0];
    double S2 = buf2[0];
    double sum_l2 = 2.0 * (double)NS * S1 - 2.0 * S2;
    double bw = sum_l2 / ((double)NS * (double)NS - (double)NS);
    bw = bw / 4.0;
    c0out[0] = (float)(1.4426950408889634 / bw);
  }
}

// ---- Kernel 3: Gram tile 128x64 + fused multi-bandwidth exp epilogue ----
// Triangular grid over asymmetric tiles: per bi, bj in [2bi, 128).
// Tiles bj in {2bi, 2bi+1} jointly tile the diagonal square once -> factor=sign
// (identical semantics to round-0 bi==bj); bj >= 2bi+2 are strictly above the
// diagonal -> factor=2*sign.
// acc[2][4] = 32 AGPRs (vs 64 at 128x128): ~112 total regs -> up to 4 blk/CU.
__global__ __launch_bounds__(256, 2) void mmd_gram(
    const unsigned short* __restrict__ Xb, const float* __restrict__ sq,
    const float* __restrict__ c0p, double* __restrict__ accK) {
  int l = blockIdx.x;
  // invert o(bi) = bi*(129-bi)  (monotone for bi<=64)
  int bi = (int)((129.f - sqrtf(16641.f - 4.f * (float)l)) * 0.5f);
  while (bi * (129 - bi) > l) bi--;
  while ((bi + 1) * (129 - (bi + 1)) <= l) bi++;
  int bj = 2 * bi + (l - bi * (129 - bi));

  __shared__ __align__(16) unsigned short As[BM * BK];  // 16 KiB
  __shared__ __align__(16) unsigned short Bs[BN * BK];  // 8 KiB
  __shared__ float red[256];
  int tid = threadIdx.x;
  int wave = tid >> 6;
  int lane = tid & 63;
  int rowBase = bi * BM, colBase = bj * BN;
  int wr = wave * 32;                  // wave's 32x64 slab of the 128x64 tile

  f32x4 acc[2][4];
#pragma unroll
  for (int m = 0; m < 2; ++m)
#pragma unroll
    for (int n = 0; n < 4; ++n) acc[m][n] = (f32x4){0.f, 0.f, 0.f, 0.f};

  for (int kt = 0; kt < DIM; kt += BK) {
    __syncthreads();  // previous compute done before overwrite
#pragma unroll
    for (int it = 0; it < 4; ++it) {   // A: 128 rows x 64 cols = 1024 x 16B
      int idx = it * 256 + tid;
      int r = idx >> 3;                // tile row 0..127
      int g = idx & 7;                 // 16B group within row
      int gs = g ^ (r & 7);            // pre-swizzled SOURCE (rule #21)
      const unsigned short* ga = Xb + (size_t)(rowBase + r) * DIM + kt + gs * 8;
      __builtin_amdgcn_global_load_lds(
          (const __attribute__((address_space(1))) void*)ga,
          (__attribute__((address_space(3))) void*)(As + idx * 8), 16, 0, 0);
    }
#pragma unroll
    for (int it = 0; it < 2; ++it) {   // B: 64 rows x 64 cols = 512 x 16B
      int idx = it * 256 + tid;
      int r = idx >> 3;                // tile row 0..63
      int g = idx & 7;
      int gs = g ^ (r & 7);
      const unsigned short* gb = Xb + (size_t)(colBase + r) * DIM + kt + gs * 8;
      __builtin_amdgcn_global_load_lds(
          (const __attribute__((address_space(1))) void*)gb,
          (__attribute__((address_space(3))) void*)(Bs + idx * 8), 16, 0, 0);
    }
    __syncthreads();  // drains vmcnt(0): staged data ready

#pragma unroll
    for (int ks = 0; ks < 2; ++ks) {
      bf16x8 af[2], bfr[4];
      int kg = ks * 4 + (lane >> 4);
#pragma unroll
      for (int m = 0; m < 2; ++m) {
        int r = wr + m * 16 + (lane & 15);
        af[m] = *(const bf16x8*)(As + r * BK + (kg ^ (r & 7)) * 8);
      }
#pragma unroll
      for (int n = 0; n < 4; ++n) {
        int r = n * 16 + (lane & 15);
        bfr[n] = *(const bf16x8*)(Bs + r * BK + (kg ^ (r & 7)) * 8);
      }
#pragma unroll
      for (int m = 0; m < 2; ++m)
#pragma unroll
        for (int n = 0; n < 4; ++n)
          acc[m][n] = __builtin_amdgcn_mfma_f32_16x16x32_bf16(
              af[m], bfr[n], acc[m][n], 0, 0, 0);
    }
  }

  // ---- epilogue: l2 -> sum of 5 Gaussians (round-0 arithmetic) ----
  float c0 = *c0p;
  float sqr[2][4], sqc[4];
  int r4 = (lane >> 4) * 4;
#pragma unroll
  for (int m = 0; m < 2; ++m)
#pragma unroll
    for (int r = 0; r < 4; ++r)
      sqr[m][r] = sq[rowBase + wr + m * 16 + r4 + r];
#pragma unroll
  for (int n = 0; n < 4; ++n)
    sqc[n] = sq[colBase + n * 16 + (lane & 15)];

  float tsum = 0.f;
#pragma unroll
  for (int m = 0; m < 2; ++m)
#pragma unroll
    for (int n = 0; n < 4; ++n)
#pragma unroll
      for (int r = 0; r < 4; ++r) {
        // C/D layout (m89): col = lane&15, row = (lane>>4)*4 + reg
        float l2 = sqr[m][r] + sqc[n] - 2.f * acc[m][n][r];
        float u = l2 * c0;
        float e4 = exp2f(-0.0625f * u);  // e_{k-1} = e_k^2
        float e3 = e4 * e4;
        float e2 = e3 * e3;
        float e1 = e2 * e2;
        float e0 = e1 * e1;
        tsum += ((e4 + e3) + (e2 + e1)) + e0;
      }

  red[tid] = tsum;
  __syncthreads();
  for (int o = 128; o > 0; o >>= 1) {
    if (tid < o) red[tid] += red[tid + o];
    __syncthreads();
  }
  if (tid == 0) {
    float sign = ((bi < HALF_MT) == (bj < HALF_NT)) ? 1.f : -1.f;
    // straddle tiles (bj < 2bi+2) jointly cover the diagonal square once
    float factor = (bj < 2 * bi + 2) ? sign : 2.f * sign;
    atomicAdd(accK, (double)(factor * red[0]));
  }
}

// ---- Kernel 4: finalize (round-0 exact) ----
__global__ void mmd_final(const double* __restrict__ accK, float* __restrict__ out) {
  out[0] = (float)(accK[0] / ((double)NHALF * (double)NHALF));
}

extern "C" void kernel_launch(void* const* d_in, const int* in_sizes, int n_in,
                              void* d_out, int out_size, void* d_ws, size_t ws_size,
                              hipStream_t stream) {
  if (ws_size < (size_t)WS_NEED) return;  // need ~4.3 MiB scratch
  const float* src = (const float*)d_in[0];
  const float* tgt = (const float*)d_in[1];
  char* ws = (char*)d_ws;
  unsigned short* Xb = (unsigned short*)(ws + XB_OFF);
  float* sq          = (float*)(ws + SQ_OFF);
  float* partials    = (float*)(ws + PART_OFF);
  double* accK       = (double*)(ws + ACC_OFF);
  float* c0          = (float*)(ws + C0_OFF);

  hipMemsetAsync(ws + ACC_OFF, 0, 16, stream);  // accK only
  mmd_prep<<<PREP_BLOCKS, 256, 0, stream>>>(src, tgt, Xb, sq, partials);
  mmd_band<<<1, 256, 0, stream>>>(partials, sq, c0);
  mmd_gram<<<NTILES_TRI, 256, 0, stream>>>(Xb, sq, c0, accK);
  mmd_final<<<1, 1, 0, stream>>>(accK, (float*)d_out);
}

// Round 4
// 69.654 us; speedup vs baseline: 2.2332x; 1.2554x over previous
//
#include <hip/hip_runtime.h>
#include <hip/hip_bf16.h>
#include <stdint.h>

#define NS 8192
#define NHALF 4096
#define DIM 256
#define BLK 128
#define BK 64
#define NKT (DIM / BK)           // 4 K-steps
#define NTILES (NS / BLK)        // 64
#define HALF_TILES (NHALF / BLK) // 32
#define NTRI (NTILES * (NTILES + 1) / 2)  // 2080 upper-tri tiles
#define PREP_BLOCKS 256

typedef __attribute__((ext_vector_type(8))) short bf16x8;
typedef __attribute__((ext_vector_type(4))) float f32x4;
typedef __attribute__((ext_vector_type(8))) unsigned short u16x8;

// workspace layout (bytes) — round-0 proven layout
#define XB_OFF   0                         // bf16 X: 8192*256*2 = 4 MiB
#define SQ_OFF   (NS * DIM * 2)            // f32 sq[8192] = 32 KiB
#define PART_OFF (SQ_OFF + NS * 4)         // f32 partials[256][256] = 256 KiB
#define ACC_OFF  (PART_OFF + PREP_BLOCKS * DIM * 4)  // f64 signed kernel sum
#define C0_OFF   (ACC_OFF + 8)             // f32 log2e / bandwidth
#define WS_NEED  (C0_OFF + 16)

__device__ __forceinline__ unsigned short f2bf(float f) {
  unsigned int u = __float_as_uint(f);
  u += 0x7fffu + ((u >> 16) & 1u);   // round-to-nearest-even
  return (unsigned short)(u >> 16);
}
__device__ __forceinline__ float bf2f(unsigned short h) {
  return __uint_as_float(((unsigned int)h) << 16);
}

// ---- Kernel 1: convert to bf16, row ||x||^2, per-block column partials ----
// (round-0 exact)
__global__ __launch_bounds__(256) void mmd_prep(
    const float* __restrict__ src, const float* __restrict__ tgt,
    unsigned short* __restrict__ Xb, float* __restrict__ sq,
    float* __restrict__ partials) {
  int tid = threadIdx.x;
  int lane32 = tid & 31;
  int rgrp = tid >> 5;
  int c = lane32 * 8;
  int rowBase = blockIdx.x * 32;

  float colpart[8];
#pragma unroll
  for (int j = 0; j < 8; ++j) colpart[j] = 0.f;

#pragma unroll
  for (int p = 0; p < 4; ++p) {
    int row = rowBase + p * 8 + rgrp;
    const float* X = (row < NHALF) ? (src + (size_t)row * DIM)
                                   : (tgt + (size_t)(row - NHALF) * DIM);
    float4 v0 = *(const float4*)(X + c);
    float4 v1 = *(const float4*)(X + c + 4);
    float vals[8] = {v0.x, v0.y, v0.z, v0.w, v1.x, v1.y, v1.z, v1.w};
    u16x8 h;
    float s = 0.f;
#pragma unroll
    for (int j = 0; j < 8; ++j) {
      unsigned short b = f2bf(vals[j]);
      h[j] = b;
      float rb = bf2f(b);
      s += rb * rb;
      colpart[j] += rb;
    }
    *(u16x8*)(Xb + (size_t)row * DIM + c) = h;
    for (int o = 16; o > 0; o >>= 1) s += __shfl_down(s, o, 32);
    if (lane32 == 0) sq[row] = s;
  }

  __shared__ float cp[8][DIM];
  *(float4*)&cp[rgrp][c]     = make_float4(colpart[0], colpart[1], colpart[2], colpart[3]);
  *(float4*)&cp[rgrp][c + 4] = make_float4(colpart[4], colpart[5], colpart[6], colpart[7]);
  __syncthreads();
  float s8 = 0.f;
#pragma unroll
  for (int r = 0; r < 8; ++r) s8 += cp[r][tid];
  partials[blockIdx.x * DIM + tid] = s8;
}

// ---- Kernel 2: reduce partials + sq -> bandwidth -> c0 (round-0 exact) ----
__global__ __launch_bounds__(256) void mmd_band(
    const float* __restrict__ partials, const float* __restrict__ sq,
    float* __restrict__ c0out) {
  __shared__ double buf2[DIM];
  __shared__ float buf1[DIM];
  int tid = threadIdx.x;
  float cs = 0.f;
  for (int b = 0; b < PREP_BLOCKS; ++b) cs += partials[b * DIM + tid];
  float s1 = 0.f;
  for (int k = 0; k < NS / DIM; ++k) s1 += sq[k * DIM + tid];
  buf2[tid] = (double)cs * (double)cs;
  buf1[tid] = s1;
  __syncthreads();
  for (int o = 128; o > 0; o >>= 1) {
    if (tid < o) { buf2[tid] += buf2[tid + o]; buf1[tid] += buf1[tid + o]; }
    __syncthreads();
  }
  if (tid == 0) {
    double S1 = (double)buf1[0];
    double S2 = buf2[0];
    double sum_l2 = 2.0 * (double)NS * S1 - 2.0 * S2;
    double bw = sum_l2 / ((double)NS * (double)NS - (double)NS);
    bw = bw / 4.0;
    c0out[0] = (float)(1.4426950408889634 / bw);
  }
}

// ---- Kernel 3: 128x128 Gram tile, 2-phase double-buffered staging ----
// Triangular 1-D grid (round-0). Per K-step: issue NEXT tile's global_load_lds
// BEFORE computing current; single __syncthreads per step (its vmcnt(0) drain
// waits on loads that had the whole compute phase to land). Epilogue reduce:
// wave shuffle (6 ops) + 1 barrier instead of 8-barrier LDS tree.
#define STAGE(KT, BUF)                                                        \
  {                                                                           \
    _Pragma("unroll") for (int it = 0; it < 4; ++it) {                        \
      int idx = it * 256 + tid;                                               \
      int r = idx >> 3, g = idx & 7, gs = g ^ (r & 7);                        \
      const unsigned short* ga =                                              \
          Xb + (size_t)(rowBase + r) * DIM + (KT)*BK + gs * 8;                \
      __builtin_amdgcn_global_load_lds(                                       \
          (const __attribute__((address_space(1))) void*)ga,                  \
          (__attribute__((address_space(3))) void*)(&As[BUF][idx * 8]), 16,   \
          0, 0);                                                              \
      const unsigned short* gb =                                              \
          Xb + (size_t)(colBase + r) * DIM + (KT)*BK + gs * 8;                \
      __builtin_amdgcn_global_load_lds(                                       \
          (const __attribute__((address_space(1))) void*)gb,                  \
          (__attribute__((address_space(3))) void*)(&Bs[BUF][idx * 8]), 16,   \
          0, 0);                                                              \
    }                                                                         \
  }

__global__ __launch_bounds__(256, 2) void mmd_gram(
    const unsigned short* __restrict__ Xb, const float* __restrict__ sq,
    const float* __restrict__ c0p, double* __restrict__ accK) {
  int l = blockIdx.x;
  int bj = (int)((sqrtf(8.f * (float)l + 1.f) - 1.f) * 0.5f);
  while ((bj + 1) * (bj + 2) / 2 <= l) bj++;
  while (bj * (bj + 1) / 2 > l) bj--;
  int bi = l - bj * (bj + 1) / 2;

  __shared__ __align__(16) unsigned short As[2][BLK * BK];  // 32 KiB
  __shared__ __align__(16) unsigned short Bs[2][BLK * BK];  // 32 KiB
  __shared__ float red4[4];
  int tid = threadIdx.x;
  int wave = tid >> 6;
  int lane = tid & 63;
  int rowBase = bi * BLK, colBase = bj * BLK;
  int wr = (wave >> 1) * 64;   // wave's 64x64 quadrant
  int wc = (wave & 1) * 64;

  f32x4 acc[4][4];
#pragma unroll
  for (int m = 0; m < 4; ++m)
#pragma unroll
    for (int n = 0; n < 4; ++n) acc[m][n] = (f32x4){0.f, 0.f, 0.f, 0.f};

  // prologue: stage K-step 0 into buffer 0 (latency exposed once)
  STAGE(0, 0);
  __syncthreads();

#pragma unroll
  for (int kt = 0; kt < NKT; ++kt) {
    int cur = kt & 1;
    if (kt < NKT - 1) STAGE(kt + 1, cur ^ 1);   // prefetch next tile

#pragma unroll
    for (int ks = 0; ks < 2; ++ks) {
      bf16x8 af[4], bfr[4];
      int kg = ks * 4 + (lane >> 4);   // 16B group index of this lane's k-slice
#pragma unroll
      for (int m = 0; m < 4; ++m) {
        int r = wr + m * 16 + (lane & 15);
        af[m] = *(const bf16x8*)(&As[cur][r * BK + (kg ^ (r & 7)) * 8]);
      }
#pragma unroll
      for (int n = 0; n < 4; ++n) {
        int r = wc + n * 16 + (lane & 15);
        bfr[n] = *(const bf16x8*)(&Bs[cur][r * BK + (kg ^ (r & 7)) * 8]);
      }
#pragma unroll
      for (int m = 0; m < 4; ++m)
#pragma unroll
        for (int n = 0; n < 4; ++n)
          acc[m][n] = __builtin_amdgcn_mfma_f32_16x16x32_bf16(
              af[m], bfr[n], acc[m][n], 0, 0, 0);
    }
    // drains vmcnt(0) (prefetch had full compute phase to land) + barrier:
    // all waves done reading buf[cur] -> safe to overwrite next iteration.
    __syncthreads();
  }

  // ---- epilogue: l2 -> sum of 5 Gaussians (1 exp2 + 4 squarings) ----
  float c0 = *c0p;
  float cE = -0.0625f * c0;      // arg = cE*(sqr+sqc) + t2*acc
  float t2 = -2.f * cE;
  float a_[4][4], b_[4];
  int r4 = (lane >> 4) * 4;
#pragma unroll
  for (int m = 0; m < 4; ++m)
#pragma unroll
    for (int r = 0; r < 4; ++r)
      a_[m][r] = cE * sq[rowBase + wr + m * 16 + r4 + r];
#pragma unroll
  for (int n = 0; n < 4; ++n)
    b_[n] = cE * sq[colBase + wc + n * 16 + (lane & 15)];

  float tsum = 0.f;
#pragma unroll
  for (int m = 0; m < 4; ++m)
#pragma unroll
    for (int n = 0; n < 4; ++n)
#pragma unroll
      for (int r = 0; r < 4; ++r) {
        // C/D layout (m89): col = lane&15, row = (lane>>4)*4 + reg
        float arg = fmaf(acc[m][n][r], t2, a_[m][r] + b_[n]);
        float e4 = exp2f(arg);           // e_{k-1} = e_k^2
        float e3 = e4 * e4;
        float e2 = e3 * e3;
        float e1 = e2 * e2;
        float e0 = e1 * e1;
        tsum += ((e4 + e3) + (e2 + e1)) + e0;
      }

  // wave-level shuffle reduce (6 ops), then tiny cross-wave combine (1 barrier)
#pragma unroll
  for (int o = 32; o > 0; o >>= 1) tsum += __shfl_down(tsum, o);
  if (lane == 0) red4[wave] = tsum;
  __syncthreads();
  if (tid == 0) {
    float t = (red4[0] + red4[1]) + (red4[2] + red4[3]);
    float sign = ((bi < HALF_TILES) == (bj < HALF_TILES)) ? 1.f : -1.f;
    float factor = (bi == bj) ? sign : 2.f * sign;  // off-diag tiles doubled
    atomicAdd(accK, (double)(factor * t));
  }
}

// ---- Kernel 4: finalize (round-0 exact) ----
__global__ void mmd_final(const double* __restrict__ accK, float* __restrict__ out) {
  out[0] = (float)(accK[0] / ((double)NHALF * (double)NHALF));
}

extern "C" void kernel_launch(void* const* d_in, const int* in_sizes, int n_in,
                              void* d_out, int out_size, void* d_ws, size_t ws_size,
                              hipStream_t stream) {
  if (ws_size < (size_t)WS_NEED) return;  // need ~4.3 MiB scratch
  const float* src = (const float*)d_in[0];
  const float* tgt = (const float*)d_in[1];
  char* ws = (char*)d_ws;
  unsigned short* Xb = (unsigned short*)(ws + XB_OFF);
  float* sq          = (float*)(ws + SQ_OFF);
  float* partials    = (float*)(ws + PART_OFF);
  double* accK       = (double*)(ws + ACC_OFF);
  float* c0          = (float*)(ws + C0_OFF);

  hipMemsetAsync(ws + ACC_OFF, 0, 16, stream);  // accK only
  mmd_prep<<<PREP_BLOCKS, 256, 0, stream>>>(src, tgt, Xb, sq, partials);
  mmd_band<<<1, 256, 0, stream>>>(partials, sq, c0);
  mmd_gram<<<NTRI, 256, 0, stream>>>(Xb, sq, c0, accK);
  mmd_final<<<1, 1, 0, stream>>>(accK, (float*)d_out);
}